// Round 4
// baseline (64.534 us; speedup 1.0000x reference)
//
#include <hip/hip_runtime.h>
#include <math.h>

// Problem constants (B,C,H,W)=(16,1,1024,1024), patch=128
constexpr int B_ = 16;
constexpr int HW = 1024;
constexpr int P  = 128;
constexpr int NPATCH = 1024;       // 16 samples * 8 * 8
constexpr int THREADS1 = 512;

// Fused: one block per 128x128 patch; last block to finish reduces the
// 1024 per-patch records and writes the scalar loss.
__global__ __launch_bounds__(THREADS1)
void fused_loss_kernel(const float* __restrict__ labels,
                       const float* __restrict__ preds,
                       float4* __restrict__ recs,
                       unsigned int* __restrict__ counter,
                       float* __restrict__ out)
{
    const int pid = blockIdx.x;
    const int s  = pid >> 6;          // sample
    const int ph = (pid >> 3) & 7;    // patch row
    const int pw = pid & 7;           // patch col
    const size_t base = (size_t)s * (HW * HW) + (size_t)ph * P * HW + (size_t)pw * P;

    const int tid  = threadIdx.x;
    const int col4 = (tid & 31) << 2; // float offset within a 128-float row
    const int row0 = tid >> 5;        // 0..15; 512 threads cover 16 rows per pass

    const float4* px = reinterpret_cast<const float4*>(preds  + base + (size_t)row0 * HW + col4);
    const float4* pt = reinterpret_cast<const float4*>(labels + base + (size_t)row0 * HW + col4);
    constexpr int STRIDE4 = 16 * HW / 4; // float4 stride for 16 rows

    // ---- Issue all 16 loads (interleaved x/t), then a hard scheduling fence
    // so the compiler cannot sink loads into the compute loop. ----
    float4 xb[8], tb[8];
    #pragma unroll
    for (int it = 0; it < 8; ++it) {
        xb[it] = px[(size_t)it * STRIDE4];
        tb[it] = pt[(size_t)it * STRIDE4];
    }
    __builtin_amdgcn_sched_barrier(0);

    // Split BCE accumulators: bce = sum_relu - sum_xt + ln2 * sum_log2(1+e)
    float sum_relu = 0.0f, sum_xt = 0.0f, sum_l2 = 0.0f;
    float xmin =  3.0e38f, xmax = -3.0e38f;
    float tmin =  3.0e38f, tmax = -3.0e38f;

    const float NLOG2E = -1.4426950408889634f; // -log2(e)

    #pragma unroll
    for (int it = 0; it < 8; ++it) {
        const float xs[4] = {xb[it].x, xb[it].y, xb[it].z, xb[it].w};
        const float ts[4] = {tb[it].x, tb[it].y, tb[it].z, tb[it].w};
        #pragma unroll
        for (int j = 0; j < 4; ++j) {
            const float x = xs[j], t = ts[j];
            const float e = __builtin_amdgcn_exp2f(fabsf(x) * NLOG2E);
            sum_l2   += __builtin_amdgcn_logf(1.0f + e);   // v_log_f32 = log2
            sum_relu += fmaxf(x, 0.0f);
            sum_xt    = fmaf(x, t, sum_xt);
            xmin = fminf(xmin, x); xmax = fmaxf(xmax, x);
            tmin = fminf(tmin, t); tmax = fmaxf(tmax, t);
        }
    }

    const float LN2 = 0.6931471805599453f;
    float bce = sum_relu - sum_xt + LN2 * sum_l2;

    // wave(64) reduction
    #pragma unroll
    for (int o = 32; o > 0; o >>= 1) {
        bce += __shfl_down(bce, o);
        xmin = fminf(xmin, __shfl_down(xmin, o));
        xmax = fmaxf(xmax, __shfl_down(xmax, o));
        tmin = fminf(tmin, __shfl_down(tmin, o));
        tmax = fmaxf(tmax, __shfl_down(tmax, o));
    }

    __shared__ float s_a[8], s_b2[8], s_c[8], s_d[8], s_e[8];
    __shared__ unsigned int s_ticket;
    const int wave = tid >> 6;
    const int lane = tid & 63;
    if (lane == 0) {
        s_a[wave] = bce;  s_b2[wave] = xmin; s_c[wave] = xmax;
        s_d[wave] = tmin; s_e[wave] = tmax;
    }
    __syncthreads();
    if (tid == 0) {
        float b = 0.0f, xi = 3.0e38f, xa = -3.0e38f, ti = 3.0e38f, ta = -3.0e38f;
        #pragma unroll
        for (int w = 0; w < THREADS1 / 64; ++w) {
            b += s_a[w];
            xi = fminf(xi, s_b2[w]); xa = fmaxf(xa, s_c[w]);
            ti = fminf(ti, s_d[w]); ta = fmaxf(ta, s_e[w]);
        }
        // valid == (min t < 0.5) && (max t > 0.5)
        const float valid = (ti < 0.5f && ta > 0.5f) ? 1.0f : 0.0f;
        recs[pid] = make_float4(b, xi, xa, valid);
        __threadfence();                       // release: record visible device-wide
        s_ticket = atomicAdd(counter, 1u);     // device-scope ticket
    }
    __syncthreads();

    // ---- Last block reduces all patch records ----
    if (s_ticket == NPATCH - 1) {
        __threadfence();                       // acquire: see all records
        float bsum = 0.0f, topo = 0.0f;
        for (int i = tid; i < NPATCH; i += THREADS1) {
            const float4 rec = recs[i];
            bsum += rec.x;
            if (rec.w > 0.5f) {
                // lh = sigmoid(1-x) decreasing in x: pmax=sig(1-xmin), pmin=sig(1-xmax)
                const float pmax = 1.0f / (1.0f + __expf(rec.y - 1.0f));
                const float pmin = 1.0f / (1.0f + __expf(rec.z - 1.0f));
                topo += (pmax - 1.0f) * (pmax - 1.0f) + pmin * pmin;
            }
        }
        #pragma unroll
        for (int o = 32; o > 0; o >>= 1) {
            bsum += __shfl_down(bsum, o);
            topo += __shfl_down(topo, o);
        }
        __syncthreads();   // re-use shared arrays safely
        if (lane == 0) { s_a[wave] = bsum; s_b2[wave] = topo; }
        __syncthreads();
        if (tid == 0) {
            float bt = 0.0f, tt = 0.0f;
            #pragma unroll
            for (int w = 0; w < THREADS1 / 64; ++w) { bt += s_a[w]; tt += s_b2[w]; }
            out[0] = bt / (float)((size_t)B_ * HW * HW) + tt / (float)B_;
        }
    }
}

extern "C" void kernel_launch(void* const* d_in, const int* in_sizes, int n_in,
                              void* d_out, int out_size, void* d_ws, size_t ws_size,
                              hipStream_t stream) {
    const float* labels = (const float*)d_in[0];
    const float* preds  = (const float*)d_in[1];
    float*  out = (float*)d_out;
    float4* recs = (float4*)d_ws;                        // 1024 * 16 B
    unsigned int* counter = (unsigned int*)((char*)d_ws + NPATCH * sizeof(float4));

    hipMemsetAsync(counter, 0, sizeof(unsigned int), stream);  // ticket = 0 each call
    fused_loss_kernel<<<NPATCH, THREADS1, 0, stream>>>(labels, preds, recs, counter, out);
}

// Round 5
// 29.930 us; speedup vs baseline: 2.1562x; 2.1562x over previous
//
#include <hip/hip_runtime.h>
#include <math.h>

// Problem constants (B,C,H,W)=(16,1,1024,1024), patch=128
constexpr int B_ = 16;
constexpr int HW = 1024;
constexpr int P  = 128;
constexpr int NPATCH = 1024;       // 16 samples * 8 * 8
constexpr int THREADS1 = 512;

#define GLOAD4(dst, addr) \
    asm volatile("global_load_dwordx4 %0, %1, off" : "=v"(dst) : "v"(addr))

// Kernel 1: one block per 128x128 patch.
// Per-patch record: {bce_partial_sum, min(pred), max(pred), valid}
__global__ __launch_bounds__(THREADS1)
void patch_stats_kernel(const float* __restrict__ labels,
                        const float* __restrict__ preds,
                        float4* __restrict__ ws)
{
    const int pid = blockIdx.x;
    const int s  = pid >> 6;          // sample
    const int ph = (pid >> 3) & 7;    // patch row
    const int pw = pid & 7;           // patch col
    const size_t base = (size_t)s * (HW * HW) + (size_t)ph * P * HW + (size_t)pw * P;

    const int tid  = threadIdx.x;
    const int col4 = (tid & 31) << 2; // float offset within a 128-float row
    const int row0 = tid >> 5;        // 0..15; 512 threads cover 16 rows per pass

    const float4* px = reinterpret_cast<const float4*>(preds  + base + (size_t)row0 * HW + col4);
    const float4* pt = reinterpret_cast<const float4*>(labels + base + (size_t)row0 * HW + col4);
    constexpr int STRIDE4 = 16 * HW / 4; // float4 stride for 16 rows

    // ---- 16 loads issued via asm volatile: fixed order, all outstanding,
    // distinct VGPR quads. Compiler cannot sink or serialize these. ----
    float4 x0, x1, x2, x3, x4, x5, x6, x7;
    float4 t0, t1, t2, t3, t4, t5, t6, t7;
    GLOAD4(x0, px + 0 * STRIDE4);  GLOAD4(t0, pt + 0 * STRIDE4);
    GLOAD4(x1, px + 1 * STRIDE4);  GLOAD4(t1, pt + 1 * STRIDE4);
    GLOAD4(x2, px + 2 * STRIDE4);  GLOAD4(t2, pt + 2 * STRIDE4);
    GLOAD4(x3, px + 3 * STRIDE4);  GLOAD4(t3, pt + 3 * STRIDE4);
    GLOAD4(x4, px + 4 * STRIDE4);  GLOAD4(t4, pt + 4 * STRIDE4);
    GLOAD4(x5, px + 5 * STRIDE4);  GLOAD4(t5, pt + 5 * STRIDE4);
    GLOAD4(x6, px + 6 * STRIDE4);  GLOAD4(t6, pt + 6 * STRIDE4);
    GLOAD4(x7, px + 7 * STRIDE4);  GLOAD4(t7, pt + 7 * STRIDE4);
    asm volatile("s_waitcnt vmcnt(0)" ::: "memory");
    __builtin_amdgcn_sched_barrier(0);   // rule #18: pin consumers after the wait

    // Split BCE accumulators: bce = sum_relu - sum_xt + ln2 * sum_log2(1+e)
    float sum_relu = 0.0f, sum_xt = 0.0f, sum_l2 = 0.0f;
    float xmin =  3.0e38f, xmax = -3.0e38f;
    float tmin =  3.0e38f, tmax = -3.0e38f;

    const float NLOG2E = -1.4426950408889634f; // -log2(e)

    const float4 xb[8] = {x0, x1, x2, x3, x4, x5, x6, x7};
    const float4 tb[8] = {t0, t1, t2, t3, t4, t5, t6, t7};
    #pragma unroll
    for (int it = 0; it < 8; ++it) {
        const float xs[4] = {xb[it].x, xb[it].y, xb[it].z, xb[it].w};
        const float ts[4] = {tb[it].x, tb[it].y, tb[it].z, tb[it].w};
        #pragma unroll
        for (int j = 0; j < 4; ++j) {
            const float x = xs[j], t = ts[j];
            const float e = __builtin_amdgcn_exp2f(fabsf(x) * NLOG2E);
            sum_l2   += __builtin_amdgcn_logf(1.0f + e);   // v_log_f32 = log2
            sum_relu += fmaxf(x, 0.0f);
            sum_xt    = fmaf(x, t, sum_xt);
            xmin = fminf(xmin, x); xmax = fmaxf(xmax, x);
            tmin = fminf(tmin, t); tmax = fmaxf(tmax, t);
        }
    }

    const float LN2 = 0.6931471805599453f;
    float bce = sum_relu - sum_xt + LN2 * sum_l2;

    // wave(64) reduction
    #pragma unroll
    for (int o = 32; o > 0; o >>= 1) {
        bce += __shfl_down(bce, o);
        xmin = fminf(xmin, __shfl_down(xmin, o));
        xmax = fmaxf(xmax, __shfl_down(xmax, o));
        tmin = fminf(tmin, __shfl_down(tmin, o));
        tmax = fmaxf(tmax, __shfl_down(tmax, o));
    }

    __shared__ float s_bce[8], s_xmin[8], s_xmax[8], s_tmin[8], s_tmax[8];
    const int wave = tid >> 6;
    const int lane = tid & 63;
    if (lane == 0) {
        s_bce[wave] = bce;  s_xmin[wave] = xmin; s_xmax[wave] = xmax;
        s_tmin[wave] = tmin; s_tmax[wave] = tmax;
    }
    __syncthreads();
    if (tid == 0) {
        float b = 0.0f, xi = 3.0e38f, xa = -3.0e38f, ti = 3.0e38f, ta = -3.0e38f;
        #pragma unroll
        for (int w = 0; w < THREADS1 / 64; ++w) {
            b += s_bce[w];
            xi = fminf(xi, s_xmin[w]); xa = fmaxf(xa, s_xmax[w]);
            ti = fminf(ti, s_tmin[w]); ta = fmaxf(ta, s_tmax[w]);
        }
        // valid == (min t < 0.5) && (max t > 0.5)
        const float valid = (ti < 0.5f && ta > 0.5f) ? 1.0f : 0.0f;
        ws[pid] = make_float4(b, xi, xa, valid);
    }
}

// Kernel 2: reduce 1024 patch records to the scalar loss. Overwrites out[0].
__global__ __launch_bounds__(1024)
void final_reduce_kernel(const float4* __restrict__ ws, float* __restrict__ out)
{
    const int tid = threadIdx.x;
    float bce = 0.0f, topo = 0.0f;
    {
        const float4 rec = ws[tid];
        bce = rec.x;
        if (rec.w > 0.5f) {
            // lh = sigmoid(1-x) decreasing in x: pmax = sig(1-xmin), pmin = sig(1-xmax)
            const float pmax = 1.0f / (1.0f + __expf(rec.y - 1.0f));
            const float pmin = 1.0f / (1.0f + __expf(rec.z - 1.0f));
            topo = (pmax - 1.0f) * (pmax - 1.0f) + pmin * pmin;
        }
    }
    #pragma unroll
    for (int o = 32; o > 0; o >>= 1) {
        bce  += __shfl_down(bce, o);
        topo += __shfl_down(topo, o);
    }
    __shared__ float s_b[16], s_t[16];
    const int wave = tid >> 6;
    const int lane = tid & 63;
    if (lane == 0) { s_b[wave] = bce; s_t[wave] = topo; }
    __syncthreads();
    if (tid == 0) {
        float bt = 0.0f, tt = 0.0f;
        #pragma unroll
        for (int w = 0; w < 16; ++w) { bt += s_b[w]; tt += s_t[w]; }
        out[0] = bt / (float)((size_t)B_ * HW * HW) + tt / (float)B_;
    }
}

extern "C" void kernel_launch(void* const* d_in, const int* in_sizes, int n_in,
                              void* d_out, int out_size, void* d_ws, size_t ws_size,
                              hipStream_t stream) {
    const float* labels = (const float*)d_in[0];
    const float* preds  = (const float*)d_in[1];
    float*  out = (float*)d_out;
    float4* ws  = (float4*)d_ws;   // 1024 * 16 B = 16 KB

    patch_stats_kernel<<<NPATCH, THREADS1, 0, stream>>>(labels, preds, ws);
    final_reduce_kernel<<<1, 1024, 0, stream>>>(ws, out);
}